// Round 3
// baseline (750.556 us; speedup 1.0000x reference)
//
#include <hip/hip_runtime.h>

// CRF NLL on MI355X, round 3: one WAVE per batch element, ZERO barriers.
// Round-2 lesson: per-step cross-wave sync costs ~1000 cyc regardless of how
// little arithmetic remains. So: 128 blocks x 64 threads, each wave runs its
// batch's scan entirely intra-wave (lockstep is free).
//
// Lane owns columns j0=2*lane, j0+1. exp(trans) fragments: 128 v2f = 256 VGPRs
// per lane (i-pairs packed so v_pk_fma needs no splats). Per step:
//   - 32 wave-uniform broadcast ds_read_b128 of the 128-float u vector
//   - 128 v_pk_fma_f32 (4 independent accumulator chains)
//   - lagged rescale by c = u_t[0]  (u[0] provably stays ~e^{+-10})
//   - ds_write_b64 of own pair into the other LDS buffer (constant-index
//     double buffer -> compiler can disambiguate, no false waits)
// feats prefetched PF=4 deep in registers.

#define BB   128
#define TT   512
#define CC   128
#define PF   4

typedef float v2f __attribute__((ext_vector_type(2)));

__global__ __launch_bounds__(64) void crf_wave(
    const float* __restrict__ feats,
    const int*   __restrict__ mask,
    const int*   __restrict__ tags,
    const float* __restrict__ trans,
    float*       __restrict__ acc)   // acc[0] += forward, acc[1] += gold score
{
    const int b    = blockIdx.x;
    const int lane = threadIdx.x;        // 0..63
    const int j0   = lane * 2;

    __shared__ __align__(16) float ubuf[2][CC];

    const float* fb = feats + (size_t)b * TT * CC;

    // ================= gold score + len (once, off the scan path) ==========
    int tg[8], mk[8];
    #pragma unroll
    for (int k = 0; k < 8; ++k) {
        const int t = k * 64 + lane;
        mk[k] = mask[b * TT + t];
        tg[k] = tags[b * TT + t];
    }
    int len = 0;
    #pragma unroll
    for (int k = 0; k < 8; ++k) len += __popcll(__ballot(mk[k]));

    float sc = 0.0f;
    #pragma unroll
    for (int k = 0; k < 8; ++k) {
        const int t = k * 64 + lane;
        // previous tag (unconditional shuffles: all lanes active)
        const int up   = __shfl_up(tg[k], 1);
        const int lst  = (k > 0) ? __shfl(tg[k - 1], 63) : (CC - 2);
        const int pv   = (lane == 0) ? lst : up;
        if (mk[k]) {
            sc += fb[(size_t)t * CC + tg[k]];        // emission
            sc += trans[pv * CC + tg[k]];            // transition into t
        }
        if (t == len - 1) sc += trans[tg[k] * CC + (CC - 1)];  // -> STOP
    }
    #pragma unroll
    for (int o = 1; o <= 32; o <<= 1) sc += __shfl_xor(sc, o);
    if (lane == 0) atomicAdd(&acc[1], sc);

    // ================= E fragments: exp(trans) columns j0,j0+1 =============
    v2f E0v[64], E1v[64];
    #pragma unroll
    for (int i2 = 0; i2 < 64; ++i2) {
        const float2 ra = *(const float2*)&trans[(size_t)(2 * i2)     * CC + j0];
        const float2 rb = *(const float2*)&trans[(size_t)(2 * i2 + 1) * CC + j0];
        v2f e0, e1;
        e0.x = __expf(ra.x); e0.y = __expf(rb.x);   // col j0, rows 2i2,2i2+1
        e1.x = __expf(ra.y); e1.y = __expf(rb.y);   // col j0+1
        E0v[i2] = e0; E1v[i2] = e1;
    }
    const float Es0 = __expf(trans[(size_t)j0       * CC + (CC - 1)]);
    const float Es1 = __expf(trans[(size_t)(j0 + 1) * CC + (CC - 1)]);

    // ================= seed: u_1 = exp(feat[0]) * E[START][:] ==============
    // (ref's -10000 init terms underflow to exactly 0 in f32, same as here)
    {
        const float2 f0 = *(const float2*)&fb[j0];
        float2 w;
        w.x = __expf(f0.x) * E0v[63].x;   // E[126][j0]
        w.y = __expf(f0.y) * E1v[63].x;   // E[126][j0+1]
        *(float2*)&ubuf[0][j0] = w;       // u_1 lives in ubuf[0]
    }
    float S = 0.0f;

    // feats prefetch for t = 1..PF
    float2 fx[PF];
    #pragma unroll
    for (int k = 0; k < PF; ++k) {
        int tn = 1 + k; tn = (tn < TT) ? tn : (TT - 1);
        fx[k] = *(const float2*)&fb[(size_t)tn * CC + j0];
    }

    // ================= scan: t = 1 .. len-1, unrolled x4 ====================
    // iteration t: reads u_t from ubuf[(t+1)&1], writes u_{t+1} to ubuf[t&1]
    for (int tb = 1; tb < len; tb += 4) {
        #pragma unroll
        for (int k = 0; k < 4; ++k) {
            const int t = tb + k;
            if (t < len) {                                   // wave-uniform
                const int rp = (t + 1) & 1;
                const float4* q = (const float4*)ubuf[rp];

                v2f a0 = {0.f, 0.f}, a1 = {0.f, 0.f};
                v2f b0 = {0.f, 0.f}, b1 = {0.f, 0.f};
                float c;
                #pragma unroll
                for (int kq = 0; kq < 32; ++kq) {
                    const float4 P = q[kq];                  // broadcast b128
                    if (kq == 0) c = P.x;                    // c = u_t[0]
                    v2f P01; P01.x = P.x; P01.y = P.y;
                    v2f P23; P23.x = P.z; P23.y = P.w;
                    a0 = __builtin_elementwise_fma(E0v[2 * kq],     P01, a0);
                    a1 = __builtin_elementwise_fma(E0v[2 * kq + 1], P23, a1);
                    b0 = __builtin_elementwise_fma(E1v[2 * kq],     P01, b0);
                    b1 = __builtin_elementwise_fma(E1v[2 * kq + 1], P23, b1);
                }
                a0 += a1; b0 += b1;
                const float s0 = a0.x + a0.y;
                const float s1 = b0.x + b0.y;

                const float rinv = __builtin_amdgcn_rcpf(c);
                S += __logf(c);
                const float e0 = __expf(fx[k].x);
                const float e1 = __expf(fx[k].y);
                float2 w;
                w.x = e0 * s0 * rinv;
                w.y = e1 * s1 * rinv;

                int tn = t + PF; tn = (tn < TT) ? tn : (TT - 1);
                fx[k] = *(const float2*)&fb[(size_t)tn * CC + j0];

                *(float2*)&ubuf[t & 1][j0] = w;              // u_{t+1}
            }
        }
    }

    // ================= terminal: log sum_j u_len[j] * exp(trans[j][STOP]) ===
    const float2 uu = *(const float2*)&ubuf[(len - 1) & 1][j0];
    float z = uu.x * Es0 + uu.y * Es1;
    #pragma unroll
    for (int o = 1; o <= 32; o <<= 1) z += __shfl_xor(z, o);
    if (lane == 0) atomicAdd(&acc[0], __logf(z) + S);
}

__global__ void crf_final(const float* __restrict__ acc, float* __restrict__ out)
{
    out[0] = (acc[0] - acc[1]) * (1.0f / (float)BB);
}

extern "C" void kernel_launch(void* const* d_in, const int* in_sizes, int n_in,
                              void* d_out, int out_size, void* d_ws, size_t ws_size,
                              hipStream_t stream)
{
    const float* feats = (const float*)d_in[0];
    const int*   mask  = (const int*)d_in[1];
    const int*   tags  = (const int*)d_in[2];
    const float* trans = (const float*)d_in[3];
    float* out = (float*)d_out;
    float* acc = (float*)d_ws;

    hipMemsetAsync(acc, 0, 2 * sizeof(float), stream);
    crf_wave<<<BB, 64, 0, stream>>>(feats, mask, tags, trans, acc);
    crf_final<<<1, 1, 0, stream>>>(acc, out);
}

// Round 4
// 404.168 us; speedup vs baseline: 1.8570x; 1.8570x over previous
//
#include <hip/hip_runtime.h>

// CRF NLL on MI355X, round 4: one wave per batch element, zero barriers,
// packed-16-bit state + dot2.
//
// Round-3 post-mortem: fp32 E fragments (2 cols/lane) = 256 VGPRs -> hard cap
// -> scratch spills (WRITE_SIZE 2 MB) -> 3400 cyc/step. Round-2 post-mortem:
// 64 ds_read_b128/step ~= 768 cyc LDS-pipe throughput was the real floor.
// Fix both: E packed bf16 (128 VGPRs), u vector in LDS packed bf16 (16
// ds_read_b128/step), v_dot2_f32_bf16 (2 MAC/inst, fp32 accum).
//
// Recurrence (probability domain, lagged rescale, proven rounds 2-3):
//   u_{t+1}[j] = exp(feat[t,j]) * (sum_i u_t[i] E[i][j]) / c_t,  S += log c_t
// c_t = u_t[0] (bf16-quantized but used consistently -> exact algebra).

#define BB 128
#define TT 512
#define CC 128
#define PF 4

#if __has_builtin(__builtin_amdgcn_fdot2_f32_bf16)
#define PATH_BF16 1
#elif __has_builtin(__builtin_amdgcn_fdot2)
#define PATH_F16 1
#else
#define PATH_FP32 1
#endif

#if defined(PATH_BF16) || defined(PATH_FP32)
// ---- storage = packed bf16 (range ~ fp32: no overflow concerns) ----
__device__ __forceinline__ unsigned packp(float x, float y) {
    unsigned xu = __builtin_bit_cast(unsigned, x);
    unsigned yu = __builtin_bit_cast(unsigned, y);
    unsigned rx = (xu + 0x7fffu + ((xu >> 16) & 1u)) >> 16;          // RNE
    unsigned ry = (yu + 0x7fffu + ((yu >> 16) & 1u)) & 0xffff0000u;  // RNE
    return rx | ry;
}
__device__ __forceinline__ float lo2f(unsigned w) {
    return __builtin_bit_cast(float, w << 16);
}
__device__ __forceinline__ float hi2f(unsigned w) {
    return __builtin_bit_cast(float, w & 0xffff0000u);
}
#if defined(PATH_BF16)
typedef __bf16 bf2v __attribute__((ext_vector_type(2)));
__device__ __forceinline__ float dot2p(unsigned a, unsigned b, float c) {
    return __builtin_amdgcn_fdot2_f32_bf16(__builtin_bit_cast(bf2v, a),
                                           __builtin_bit_cast(bf2v, b), c, false);
}
#else
__device__ __forceinline__ float dot2p(unsigned a, unsigned b, float c) {
    return fmaf(hi2f(a), hi2f(b), fmaf(lo2f(a), lo2f(b), c));
}
#endif
#else
// ---- f16 fallback: limited range -> rescale by exact per-step max ----
#define RESCALE_MAX 1
typedef _Float16 h2v __attribute__((ext_vector_type(2)));
__device__ __forceinline__ unsigned packp(float x, float y) {
    h2v h = __builtin_amdgcn_cvt_pkrtz(x, y);
    return __builtin_bit_cast(unsigned, h);
}
__device__ __forceinline__ float lo2f(unsigned w) {
    h2v h = __builtin_bit_cast(h2v, w); return (float)h.x;
}
__device__ __forceinline__ float hi2f(unsigned w) {
    h2v h = __builtin_bit_cast(h2v, w); return (float)h.y;
}
__device__ __forceinline__ float dot2p(unsigned a, unsigned b, float c) {
    return __builtin_amdgcn_fdot2(__builtin_bit_cast(h2v, a),
                                  __builtin_bit_cast(h2v, b), c, false);
}
#endif

__global__ __launch_bounds__(64, 1) void crf_wave(
    const float* __restrict__ feats,
    const int*   __restrict__ mask,
    const int*   __restrict__ tags,
    const float* __restrict__ trans,
    float*       __restrict__ acc)   // acc[0] += forward, acc[1] += gold score
{
    const int b    = blockIdx.x;
    const int lane = threadIdx.x;        // 0..63
    const int j0   = lane * 2;           // this lane's two state columns

    __shared__ __align__(16) unsigned ubuf[2][CC / 2];  // packed-16 u, dbuf

    const float* fb = feats + (size_t)b * TT * CC;

    // ================= gold score + len (off the scan path) ================
    {
        int tg[8], mk[8];
        #pragma unroll
        for (int k = 0; k < 8; ++k) {
            const int t = k * 64 + lane;
            mk[k] = mask[b * TT + t];
            tg[k] = tags[b * TT + t];
        }
        int len_ = 0;
        #pragma unroll
        for (int k = 0; k < 8; ++k) len_ += __popcll(__ballot(mk[k]));

        float sc = 0.0f;
        #pragma unroll
        for (int k = 0; k < 8; ++k) {
            const int t   = k * 64 + lane;
            const int up  = __shfl_up(tg[k], 1);
            const int lst = (k > 0) ? __shfl(tg[k - 1], 63) : (CC - 2);
            const int pv  = (lane == 0) ? lst : up;
            if (mk[k]) {
                sc += fb[(size_t)t * CC + tg[k]];       // emission
                sc += trans[pv * CC + tg[k]];           // transition into t
            }
            if (t == len_ - 1) sc += trans[tg[k] * CC + (CC - 1)];  // -> STOP
        }
        #pragma unroll
        for (int o = 1; o <= 32; o <<= 1) sc += __shfl_xor(sc, o);
        if (lane == 0) atomicAdd(&acc[1], sc);
    }

    const int len = [&] {
        int l = 0;
        #pragma unroll
        for (int k = 0; k < 8; ++k)
            l += __popcll(__ballot(mask[b * TT + k * 64 + lane]));
        return l;
    }();

    // ===== E fragments: packed 16-bit pairs of exp(trans), 128 VGPRs =======
    // E0[p] = pack(E[2p][j0],   E[2p+1][j0])
    // E1[p] = pack(E[2p][j0+1], E[2p+1][j0+1])
    unsigned E0[64], E1[64];
    #pragma unroll
    for (int p = 0; p < 64; ++p) {
        const float2 ta = *(const float2*)&trans[(size_t)(2 * p)     * CC + j0];
        const float2 tb = *(const float2*)&trans[(size_t)(2 * p + 1) * CC + j0];
        E0[p] = packp(__expf(ta.x), __expf(tb.x));
        E1[p] = packp(__expf(ta.y), __expf(tb.y));
    }
    const float Es0 = __expf(trans[(size_t)j0       * CC + (CC - 1)]);
    const float Es1 = __expf(trans[(size_t)(j0 + 1) * CC + (CC - 1)]);

    // ================= seed u_1 = exp(feat[0]) * E[START][:] ===============
    float S = 0.0f;
    {
        const float2 f0 = *(const float2*)&fb[j0];
        const float tEx = __expf(trans[(size_t)(CC - 2) * CC + j0]);
        const float tEy = __expf(trans[(size_t)(CC - 2) * CC + j0 + 1]);
        float vx = __expf(f0.x) * tEx;
        float vy = __expf(f0.y) * tEy;
#ifdef RESCALE_MAX
        float m = fmaxf(vx, vy);
        #pragma unroll
        for (int o = 1; o <= 32; o <<= 1) m = fmaxf(m, __shfl_xor(m, o));
        const float ri = __builtin_amdgcn_rcpf(m);
        S += __logf(m);
        vx *= ri; vy *= ri;
#endif
        ubuf[0][lane] = packp(vx, vy);
    }

    // feats prefetch, PF deep
    float2 fx[PF];
    #pragma unroll
    for (int k = 0; k < PF; ++k) {
        int tn = 1 + k; tn = (tn < TT) ? tn : (TT - 1);
        fx[k] = *(const float2*)&fb[(size_t)tn * CC + j0];
    }

    // ================= scan t = 1 .. len-1 (u_t in ubuf[(t+1)&1]) ==========
    for (int tb2 = 1; tb2 < len; tb2 += 4) {
        #pragma unroll
        for (int k = 0; k < 4; ++k) {
            const int t = tb2 + k;
            if (t < len) {                               // wave-uniform
                const uint4* q = (const uint4*)&ubuf[(t + 1) & 1][0];
                float a0 = 0.f, a1 = 0.f, a2 = 0.f, a3 = 0.f;
                float c0 = 0.f, c1 = 0.f, c2 = 0.f, c3 = 0.f;
                float cs = 1.0f;
                #pragma unroll
                for (int kq = 0; kq < 16; ++kq) {
                    const uint4 P = q[kq];               // broadcast b128
                    if (kq == 0) cs = lo2f(P.x);         // c = u_t[0]
                    const int p = kq * 4;
                    a0 = dot2p(E0[p + 0], P.x, a0);
                    a1 = dot2p(E0[p + 1], P.y, a1);
                    a2 = dot2p(E0[p + 2], P.z, a2);
                    a3 = dot2p(E0[p + 3], P.w, a3);
                    c0 = dot2p(E1[p + 0], P.x, c0);
                    c1 = dot2p(E1[p + 1], P.y, c1);
                    c2 = dot2p(E1[p + 2], P.z, c2);
                    c3 = dot2p(E1[p + 3], P.w, c3);
                }
                const float s0 = (a0 + a1) + (a2 + a3);
                const float s1 = (c0 + c1) + (c2 + c3);
                const float e0 = __expf(fx[k].x);
                const float e1 = __expf(fx[k].y);

                int tn = t + PF; tn = (tn < TT) ? tn : (TT - 1);
                fx[k] = *(const float2*)&fb[(size_t)tn * CC + j0];

#ifdef RESCALE_MAX
                float vx = e0 * s0, vy = e1 * s1;        // fp32-safe pre-scale
                float m = fmaxf(vx, vy);
                #pragma unroll
                for (int o = 1; o <= 32; o <<= 1) m = fmaxf(m, __shfl_xor(m, o));
                const float ri = __builtin_amdgcn_rcpf(m);
                S += __logf(m);
                ubuf[t & 1][lane] = packp(vx * ri, vy * ri);
#else
                const float ri = __builtin_amdgcn_rcpf(cs);
                S += __logf(cs);
                ubuf[t & 1][lane] = packp(e0 * s0 * ri, e1 * s1 * ri);
#endif
            }
        }
    }

    // ======= terminal: log sum_j u_len[j] * exp(trans[j][STOP]) + S ========
    const unsigned uw = ubuf[(len - 1) & 1][lane];
    float z = lo2f(uw) * Es0 + hi2f(uw) * Es1;
    #pragma unroll
    for (int o = 1; o <= 32; o <<= 1) z += __shfl_xor(z, o);
    if (lane == 0) atomicAdd(&acc[0], __logf(z) + S);
}

__global__ void crf_final(const float* __restrict__ acc, float* __restrict__ out)
{
    out[0] = (acc[0] - acc[1]) * (1.0f / (float)BB);
}

extern "C" void kernel_launch(void* const* d_in, const int* in_sizes, int n_in,
                              void* d_out, int out_size, void* d_ws, size_t ws_size,
                              hipStream_t stream)
{
    const float* feats = (const float*)d_in[0];
    const int*   mask  = (const int*)d_in[1];
    const int*   tags  = (const int*)d_in[2];
    const float* trans = (const float*)d_in[3];
    float* out = (float*)d_out;
    float* acc = (float*)d_ws;

    hipMemsetAsync(acc, 0, 2 * sizeof(float), stream);
    crf_wave<<<BB, 64, 0, stream>>>(feats, mask, tags, trans, acc);
    crf_final<<<1, 1, 0, stream>>>(acc, out);
}

// Round 5
// 322.399 us; speedup vs baseline: 2.3280x; 1.2536x over previous
//
#include <hip/hip_runtime.h>

// CRF NLL on MI355X, round 5: round-4 structure + forced 1-wave/EU occupancy.
//
// Round-4 post-mortem: VGPR_Count=84 with >=128 live E values and zero
// scratch traffic -> compiler spilled E to AGPRs (unified file) and the
// inner loop paid ~128 v_accvgpr_read/step -> 1660 cyc/step. launch_bounds'
// 2nd arg is only a MIN waves/EU; the allocator still chased occupancy.
// Fix: amdgpu_waves_per_eu(1,1) pins occupancy to 1 wave/EU (we run 1 wave
// per block, 128 blocks on 256 CUs -- multi-wave occupancy buys nothing),
// so E0/E1 (128 regs) stay in arch VGPRs.
//
// Recurrence (probability domain, lagged rescale, proven rounds 2-4):
//   u_{t+1}[j] = exp(feat[t,j]) * (sum_i u_t[i] E[i][j]) / c_t,  S += log c_t

#define BB 128
#define TT 512
#define CC 128
#define PF 4

#if __has_builtin(__builtin_amdgcn_fdot2_f32_bf16)
#define PATH_BF16 1
#elif __has_builtin(__builtin_amdgcn_fdot2)
#define PATH_F16 1
#else
#define PATH_FP32 1
#endif

#if defined(PATH_BF16) || defined(PATH_FP32)
// ---- storage = packed bf16 (range ~ fp32: no overflow concerns) ----
__device__ __forceinline__ unsigned packp(float x, float y) {
    unsigned xu = __builtin_bit_cast(unsigned, x);
    unsigned yu = __builtin_bit_cast(unsigned, y);
    unsigned rx = (xu + 0x7fffu + ((xu >> 16) & 1u)) >> 16;          // RNE
    unsigned ry = (yu + 0x7fffu + ((yu >> 16) & 1u)) & 0xffff0000u;  // RNE
    return rx | ry;
}
__device__ __forceinline__ float lo2f(unsigned w) {
    return __builtin_bit_cast(float, w << 16);
}
__device__ __forceinline__ float hi2f(unsigned w) {
    return __builtin_bit_cast(float, w & 0xffff0000u);
}
#if defined(PATH_BF16)
typedef __bf16 bf2v __attribute__((ext_vector_type(2)));
__device__ __forceinline__ float dot2p(unsigned a, unsigned b, float c) {
    return __builtin_amdgcn_fdot2_f32_bf16(__builtin_bit_cast(bf2v, a),
                                           __builtin_bit_cast(bf2v, b), c, false);
}
#else
__device__ __forceinline__ float dot2p(unsigned a, unsigned b, float c) {
    return fmaf(hi2f(a), hi2f(b), fmaf(lo2f(a), lo2f(b), c));
}
#endif
#else
// ---- f16 fallback: limited range -> rescale by exact per-step max ----
#define RESCALE_MAX 1
typedef _Float16 h2v __attribute__((ext_vector_type(2)));
__device__ __forceinline__ unsigned packp(float x, float y) {
    h2v h = __builtin_amdgcn_cvt_pkrtz(x, y);
    return __builtin_bit_cast(unsigned, h);
}
__device__ __forceinline__ float lo2f(unsigned w) {
    h2v h = __builtin_bit_cast(h2v, w); return (float)h.x;
}
__device__ __forceinline__ float hi2f(unsigned w) {
    h2v h = __builtin_bit_cast(h2v, w); return (float)h.y;
}
__device__ __forceinline__ float dot2p(unsigned a, unsigned b, float c) {
    return __builtin_amdgcn_fdot2(__builtin_bit_cast(h2v, a),
                                  __builtin_bit_cast(h2v, b), c, false);
}
#endif

__attribute__((amdgpu_waves_per_eu(1, 1)))
__global__ __launch_bounds__(64) void crf_wave(
    const float* __restrict__ feats,
    const int*   __restrict__ mask,
    const int*   __restrict__ tags,
    const float* __restrict__ trans,
    float*       __restrict__ acc)   // acc[0] += forward, acc[1] += gold score
{
    const int b    = blockIdx.x;
    const int lane = threadIdx.x;        // 0..63
    const int j0   = lane * 2;           // this lane's two state columns

    __shared__ __align__(16) unsigned ubuf[2][CC / 2];  // packed-16 u, dbuf

    const float* fb = feats + (size_t)b * TT * CC;

    // ================= gold score + len (off the scan path) ================
    {
        int tg[8], mk[8];
        #pragma unroll
        for (int k = 0; k < 8; ++k) {
            const int t = k * 64 + lane;
            mk[k] = mask[b * TT + t];
            tg[k] = tags[b * TT + t];
        }
        int len_ = 0;
        #pragma unroll
        for (int k = 0; k < 8; ++k) len_ += __popcll(__ballot(mk[k]));

        float sc = 0.0f;
        #pragma unroll
        for (int k = 0; k < 8; ++k) {
            const int t   = k * 64 + lane;
            const int up  = __shfl_up(tg[k], 1);
            const int lst = (k > 0) ? __shfl(tg[k - 1], 63) : (CC - 2);
            const int pv  = (lane == 0) ? lst : up;
            if (mk[k]) {
                sc += fb[(size_t)t * CC + tg[k]];       // emission
                sc += trans[pv * CC + tg[k]];           // transition into t
            }
            if (t == len_ - 1) sc += trans[tg[k] * CC + (CC - 1)];  // -> STOP
        }
        #pragma unroll
        for (int o = 1; o <= 32; o <<= 1) sc += __shfl_xor(sc, o);
        if (lane == 0) atomicAdd(&acc[1], sc);
    }

    const int len = [&] {
        int l = 0;
        #pragma unroll
        for (int k = 0; k < 8; ++k)
            l += __popcll(__ballot(mask[b * TT + k * 64 + lane]));
        return l;
    }();

    // ===== E fragments: packed 16-bit pairs of exp(trans), 128 VGPRs =======
    // E0[p] = pack(E[2p][j0],   E[2p+1][j0])
    // E1[p] = pack(E[2p][j0+1], E[2p+1][j0+1])
    unsigned E0[64], E1[64];
    #pragma unroll
    for (int p = 0; p < 64; ++p) {
        const float2 ta = *(const float2*)&trans[(size_t)(2 * p)     * CC + j0];
        const float2 tb = *(const float2*)&trans[(size_t)(2 * p + 1) * CC + j0];
        E0[p] = packp(__expf(ta.x), __expf(tb.x));
        E1[p] = packp(__expf(ta.y), __expf(tb.y));
    }
    const float Es0 = __expf(trans[(size_t)j0       * CC + (CC - 1)]);
    const float Es1 = __expf(trans[(size_t)(j0 + 1) * CC + (CC - 1)]);

    // ================= seed u_1 = exp(feat[0]) * E[START][:] ===============
    float S = 0.0f;
    {
        const float2 f0 = *(const float2*)&fb[j0];
        const float tEx = __expf(trans[(size_t)(CC - 2) * CC + j0]);
        const float tEy = __expf(trans[(size_t)(CC - 2) * CC + j0 + 1]);
        float vx = __expf(f0.x) * tEx;
        float vy = __expf(f0.y) * tEy;
#ifdef RESCALE_MAX
        float m = fmaxf(vx, vy);
        #pragma unroll
        for (int o = 1; o <= 32; o <<= 1) m = fmaxf(m, __shfl_xor(m, o));
        const float ri = __builtin_amdgcn_rcpf(m);
        S += __logf(m);
        vx *= ri; vy *= ri;
#endif
        ubuf[0][lane] = packp(vx, vy);
    }

    // feats prefetch, PF deep
    float2 fx[PF];
    #pragma unroll
    for (int k = 0; k < PF; ++k) {
        int tn = 1 + k; tn = (tn < TT) ? tn : (TT - 1);
        fx[k] = *(const float2*)&fb[(size_t)tn * CC + j0];
    }

    // ================= scan t = 1 .. len-1 (u_t in ubuf[(t+1)&1]) ==========
    for (int tb2 = 1; tb2 < len; tb2 += 4) {
        #pragma unroll
        for (int k = 0; k < 4; ++k) {
            const int t = tb2 + k;
            if (t < len) {                               // wave-uniform
                const uint4* q = (const uint4*)&ubuf[(t + 1) & 1][0];
                float a0 = 0.f, a1 = 0.f, a2 = 0.f, a3 = 0.f;
                float c0 = 0.f, c1 = 0.f, c2 = 0.f, c3 = 0.f;
                float cs = 1.0f;
                #pragma unroll
                for (int kq = 0; kq < 16; ++kq) {
                    const uint4 P = q[kq];               // broadcast b128
                    if (kq == 0) cs = lo2f(P.x);         // c = u_t[0]
                    const int p = kq * 4;
                    a0 = dot2p(E0[p + 0], P.x, a0);
                    a1 = dot2p(E0[p + 1], P.y, a1);
                    a2 = dot2p(E0[p + 2], P.z, a2);
                    a3 = dot2p(E0[p + 3], P.w, a3);
                    c0 = dot2p(E1[p + 0], P.x, c0);
                    c1 = dot2p(E1[p + 1], P.y, c1);
                    c2 = dot2p(E1[p + 2], P.z, c2);
                    c3 = dot2p(E1[p + 3], P.w, c3);
                }
                const float s0 = (a0 + a1) + (a2 + a3);
                const float s1 = (c0 + c1) + (c2 + c3);
                const float e0 = __expf(fx[k].x);
                const float e1 = __expf(fx[k].y);

                int tn = t + PF; tn = (tn < TT) ? tn : (TT - 1);
                fx[k] = *(const float2*)&fb[(size_t)tn * CC + j0];

#ifdef RESCALE_MAX
                float vx = e0 * s0, vy = e1 * s1;        // fp32-safe pre-scale
                float m = fmaxf(vx, vy);
                #pragma unroll
                for (int o = 1; o <= 32; o <<= 1) m = fmaxf(m, __shfl_xor(m, o));
                const float ri = __builtin_amdgcn_rcpf(m);
                S += __logf(m);
                ubuf[t & 1][lane] = packp(vx * ri, vy * ri);
#else
                const float ri = __builtin_amdgcn_rcpf(cs);
                S += __logf(cs);
                ubuf[t & 1][lane] = packp(e0 * s0 * ri, e1 * s1 * ri);
#endif
            }
        }
    }

    // ======= terminal: log sum_j u_len[j] * exp(trans[j][STOP]) + S ========
    const unsigned uw = ubuf[(len - 1) & 1][lane];
    float z = lo2f(uw) * Es0 + hi2f(uw) * Es1;
    #pragma unroll
    for (int o = 1; o <= 32; o <<= 1) z += __shfl_xor(z, o);
    if (lane == 0) atomicAdd(&acc[0], __logf(z) + S);
}

__global__ void crf_final(const float* __restrict__ acc, float* __restrict__ out)
{
    out[0] = (acc[0] - acc[1]) * (1.0f / (float)BB);
}

extern "C" void kernel_launch(void* const* d_in, const int* in_sizes, int n_in,
                              void* d_out, int out_size, void* d_ws, size_t ws_size,
                              hipStream_t stream)
{
    const float* feats = (const float*)d_in[0];
    const int*   mask  = (const int*)d_in[1];
    const int*   tags  = (const int*)d_in[2];
    const float* trans = (const float*)d_in[3];
    float* out = (float*)d_out;
    float* acc = (float*)d_ws;

    hipMemsetAsync(acc, 0, 2 * sizeof(float), stream);
    crf_wave<<<BB, 64, 0, stream>>>(feats, mask, tags, trans, acc);
    crf_final<<<1, 1, 0, stream>>>(acc, out);
}